// Round 1
// baseline (1127.605 us; speedup 1.0000x reference)
//
#include <hip/hip_runtime.h>

// QBN_GRU_Base on MI355X.
// Key idea: ternary bottlenecks (dim 8) make the recurrence finite-state:
//   xq, q in {-1,0,1}^8 -> 6561 codes. Memoize
//     GI[code][48]   = xq@wih.T + bih            (packed [i*4+{r,z,n,pad}])
//     GHM[code][64]  = {m@whh.T + bhh, m}        (packed [i*4+{r,z,n,m}], row 6561 = h0=0 state)
//     Y[code][16]    = tanh(m@act_w.T + act_b)
// Scan step = 2 table-row loads + gates + m2q (640 MAC) across 16 lanes/elem.
// Output = gather of Y rows.
// Numerics: XLA/Eigen rational tanh, logistic = 0.5+0.5*tanh(0.5x), fma dots.

#define T_DIM 512
#define B_DIM 2048
#define NELEM (T_DIM * B_DIM)

__device__ __forceinline__ float tanh_xla(float x) {
  // Eigen/XLA generic_fast_tanh_float
  const float kClamp = 7.99881172180175781f;
  float xc = fminf(fmaxf(x, -kClamp), kClamp);
  float x2 = xc * xc;
  float p = fmaf(x2, -2.76076847742355e-16f, 2.00018790482477e-13f);
  p = fmaf(x2, p, -8.60467152213735e-11f);
  p = fmaf(x2, p, 5.12229709037114e-08f);
  p = fmaf(x2, p, 1.48572235717979e-05f);
  p = fmaf(x2, p, 6.37261928875436e-04f);
  p = fmaf(x2, p, 4.89352455891786e-03f);
  p = xc * p;
  float q = fmaf(x2, 1.19825839466702e-06f, 1.18534705686654e-04f);
  q = fmaf(x2, q, 2.26843463243900e-03f);
  q = fmaf(x2, q, 4.89352518554385e-03f);
  float r = p / q;
  return (fabsf(x) < 0.0004f) ? x : r;
}

__device__ __forceinline__ float sigmoid_xla(float x) {
  // XLA LogisticExpander: logistic(x) = 0.5 + 0.5*tanh(0.5*x)
  return 0.5f + 0.5f * tanh_xla(0.5f * x);
}

__device__ __forceinline__ int ternary_digit(float v) {
  // round(1.5*tanh(v) + 0.5*tanh(-3v)) + 1  in {0,1,2}; rintf = round-half-even
  float soft = 1.5f * tanh_xla(v) + 0.5f * tanh_xla(-3.0f * v);
  return (int)rintf(soft) + 1;
}

// ---------------- K1: obs encoder -> xcode[T*B] ----------------
__global__ __launch_bounds__(256) void k_obs(
    const float* __restrict__ x,
    const float* __restrict__ w0, const float* __restrict__ b0,
    const float* __restrict__ w1, const float* __restrict__ b1,
    const float* __restrict__ w2, const float* __restrict__ b2,
    unsigned short* __restrict__ xcodes) {
  int e = blockIdx.x * 256 + threadIdx.x;  // grid is exact
  const float* xr = x + (size_t)e * 64;
  float xv[64];
#pragma unroll
  for (int j = 0; j < 64; j += 4) {
    float4 v = *reinterpret_cast<const float4*>(xr + j);
    xv[j] = v.x; xv[j + 1] = v.y; xv[j + 2] = v.z; xv[j + 3] = v.w;
  }
  float h1[28];
#pragma unroll
  for (int k = 0; k < 28; ++k) {
    float acc = 0.0f;
#pragma unroll
    for (int j = 0; j < 64; ++j) acc = fmaf(w0[k * 64 + j], xv[j], acc);
    h1[k] = tanh_xla(acc + b0[k]);
  }
  float h2[28];
#pragma unroll
  for (int k = 0; k < 28; ++k) {
    float acc = 0.0f;
#pragma unroll
    for (int j = 0; j < 28; ++j) acc = fmaf(w1[k * 28 + j], h1[j], acc);
    h2[k] = tanh_xla(acc + b1[k]);
  }
  const int p3[8] = {1, 3, 9, 27, 81, 243, 729, 2187};
  unsigned code = 0;
#pragma unroll
  for (int k = 0; k < 8; ++k) {
    float acc = 0.0f;
#pragma unroll
    for (int j = 0; j < 28; ++j) acc = fmaf(w2[k * 28 + j], h2[j], acc);
    code += (unsigned)(ternary_digit(acc + b2[k]) * p3[k]);
  }
  xcodes[e] = (unsigned short)code;
}

// ---------------- K2: GI table [6561][64] ----------------
__global__ __launch_bounds__(256) void k_gi(
    const float* __restrict__ wih, const float* __restrict__ bih,
    float* __restrict__ gip) {
  int c = blockIdx.x * 256 + threadIdx.x;
  if (c >= 6561) return;
  float q[8];
  unsigned cc = (unsigned)c;
#pragma unroll
  for (int k = 0; k < 8; ++k) { q[k] = (float)((int)(cc % 3u) - 1); cc /= 3u; }
#pragma unroll
  for (int i = 0; i < 16; ++i) {
    float gr = 0.f, gz = 0.f, gn = 0.f;
#pragma unroll
    for (int j = 0; j < 8; ++j) {
      gr = fmaf(wih[i * 8 + j], q[j], gr);
      gz = fmaf(wih[(16 + i) * 8 + j], q[j], gz);
      gn = fmaf(wih[(32 + i) * 8 + j], q[j], gn);
    }
    float4 o;
    o.x = gr + bih[i]; o.y = gz + bih[16 + i]; o.z = gn + bih[32 + i]; o.w = 0.f;
    *reinterpret_cast<float4*>(gip + (size_t)c * 64 + i * 4) = o;
  }
}

// ---------------- K3: GHM [6562][64] + Y [6561][16] ----------------
__global__ __launch_bounds__(256) void k_mtab(
    const float* __restrict__ q2m_w0, const float* __restrict__ q2m_b0,
    const float* __restrict__ q2m_w1, const float* __restrict__ q2m_b1,
    const float* __restrict__ q2m_w2, const float* __restrict__ q2m_b2,
    const float* __restrict__ whh, const float* __restrict__ bhh,
    const float* __restrict__ act_w, const float* __restrict__ act_b,
    float* __restrict__ ghm, float* __restrict__ ytab) {
  int c = blockIdx.x * 256 + threadIdx.x;
  if (c > 6561) return;
  float m[16];
  if (c == 6561) {
#pragma unroll
    for (int i = 0; i < 16; ++i) m[i] = 0.0f;  // h0 = 0
  } else {
    float q[8];
    unsigned cc = (unsigned)c;
#pragma unroll
    for (int k = 0; k < 8; ++k) { q[k] = (float)((int)(cc % 3u) - 1); cc /= 3u; }
    float a[16];
#pragma unroll
    for (int i = 0; i < 16; ++i) {
      float acc = 0.f;
#pragma unroll
      for (int j = 0; j < 8; ++j) acc = fmaf(q2m_w0[i * 8 + j], q[j], acc);
      a[i] = tanh_xla(acc + q2m_b0[i]);
    }
    float d[16];
#pragma unroll
    for (int i = 0; i < 16; ++i) {
      float acc = 0.f;
#pragma unroll
      for (int j = 0; j < 16; ++j) acc = fmaf(q2m_w1[i * 16 + j], a[j], acc);
      d[i] = tanh_xla(acc + q2m_b1[i]);
    }
#pragma unroll
    for (int i = 0; i < 16; ++i) {
      float acc = 0.f;
#pragma unroll
      for (int j = 0; j < 16; ++j) acc = fmaf(q2m_w2[i * 16 + j], d[j], acc);
      m[i] = tanh_xla(acc + q2m_b2[i]);
    }
  }
#pragma unroll
  for (int i = 0; i < 16; ++i) {
    float gr = 0.f, gz = 0.f, gn = 0.f;
#pragma unroll
    for (int j = 0; j < 16; ++j) {
      gr = fmaf(whh[i * 16 + j], m[j], gr);
      gz = fmaf(whh[(16 + i) * 16 + j], m[j], gz);
      gn = fmaf(whh[(32 + i) * 16 + j], m[j], gn);
    }
    float4 o;
    o.x = gr + bhh[i]; o.y = gz + bhh[16 + i]; o.z = gn + bhh[32 + i]; o.w = m[i];
    *reinterpret_cast<float4*>(ghm + (size_t)c * 64 + i * 4) = o;
  }
  if (c < 6561) {
#pragma unroll
    for (int i = 0; i < 16; ++i) {
      float acc = 0.f;
#pragma unroll
      for (int j = 0; j < 16; ++j) acc = fmaf(act_w[i * 16 + j], m[j], acc);
      ytab[(size_t)c * 16 + i] = tanh_xla(acc + act_b[i]);
    }
  }
}

// ---------------- K4: the scan. 16 lanes per batch element ----------------
__global__ __launch_bounds__(64) void k_scan(
    const unsigned short* __restrict__ xcodes,
    const float* __restrict__ ghm,  // [6562][64]
    const float* __restrict__ gip,  // [6561][64]
    const float* __restrict__ m2q_w0, const float* __restrict__ m2q_b0,
    const float* __restrict__ m2q_w1, const float* __restrict__ m2q_b1,
    const float* __restrict__ m2q_w2, const float* __restrict__ m2q_b2,
    unsigned short* __restrict__ qcodes) {
  int lane = threadIdx.x & 15;
  int b = (blockIdx.x * 64 + threadIdx.x) >> 4;  // 0..2047
  // per-lane m2q weight rows
  float w0r[16], w1r[16], w2r[16];
#pragma unroll
  for (int j = 0; j < 16; j += 4) {
    float4 a = *reinterpret_cast<const float4*>(m2q_w0 + lane * 16 + j);
    w0r[j] = a.x; w0r[j + 1] = a.y; w0r[j + 2] = a.z; w0r[j + 3] = a.w;
    float4 bq = *reinterpret_cast<const float4*>(m2q_w1 + lane * 16 + j);
    w1r[j] = bq.x; w1r[j + 1] = bq.y; w1r[j + 2] = bq.z; w1r[j + 3] = bq.w;
    float4 cq = *reinterpret_cast<const float4*>(m2q_w2 + (lane & 7) * 16 + j);
    w2r[j] = cq.x; w2r[j + 1] = cq.y; w2r[j + 2] = cq.z; w2r[j + 3] = cq.w;
  }
  float b0l = m2q_b0[lane], b1l = m2q_b1[lane], b2l = m2q_b2[lane & 7];
  const int ip3[8] = {1, 3, 9, 27, 81, 243, 729, 2187};
  int p3 = (lane < 8) ? ip3[lane & 7] : 0;

  unsigned qprev = 6561;  // initial-state row
  unsigned xc = xcodes[b];
  float4 i4 = *reinterpret_cast<const float4*>(gip + (size_t)xc * 64 + lane * 4);

  for (int t = 0; t < T_DIM; ++t) {
    float4 g4 = *reinterpret_cast<const float4*>(ghm + (size_t)qprev * 64 + lane * 4);
    // prefetch next step's GI row (independent of qprev chain)
    int tn = (t + 1 < T_DIM) ? t + 1 : T_DIM - 1;
    unsigned xcn = xcodes[tn * B_DIM + b];
    float4 i4n = *reinterpret_cast<const float4*>(gip + (size_t)xcn * 64 + lane * 4);

    float r = sigmoid_xla(i4.x + g4.x);
    float z = sigmoid_xla(i4.y + g4.y);
    float n = tanh_xla(fmaf(r, g4.z, i4.z));
    float h = (1.0f - z) * n + z * g4.w;

    float acc = 0.f;
#pragma unroll
    for (int j = 0; j < 16; ++j) acc = fmaf(w0r[j], __shfl(h, j, 16), acc);
    float t0 = tanh_xla(acc + b0l);
    acc = 0.f;
#pragma unroll
    for (int j = 0; j < 16; ++j) acc = fmaf(w1r[j], __shfl(t0, j, 16), acc);
    float t1 = tanh_xla(acc + b1l);
    acc = 0.f;
#pragma unroll
    for (int j = 0; j < 16; ++j) acc = fmaf(w2r[j], __shfl(t1, j, 16), acc);
    int val = ternary_digit(acc + b2l) * p3;  // lanes 8..15 contribute 0
    val += __shfl_xor(val, 1, 16);
    val += __shfl_xor(val, 2, 16);
    val += __shfl_xor(val, 4, 16);
    val += __shfl_xor(val, 8, 16);
    qprev = (unsigned)val;
    if (lane == 0) qcodes[t * B_DIM + b] = (unsigned short)qprev;
    xc = xcn;
    i4 = i4n;
  }
}

// ---------------- K5: output gather out[e] = Y[qcode[e]] ----------------
__global__ __launch_bounds__(256) void k_out(
    const unsigned short* __restrict__ qcodes,
    const float* __restrict__ ytab,
    float* __restrict__ out) {
  int i = blockIdx.x * 256 + threadIdx.x;  // over NELEM*4 float4s, grid exact
  int e = i >> 2, sub = i & 3;
  unsigned c = qcodes[e];
  float4 y = *reinterpret_cast<const float4*>(ytab + (size_t)c * 16 + sub * 4);
  reinterpret_cast<float4*>(out)[i] = y;
}

extern "C" void kernel_launch(void* const* d_in, const int* in_sizes, int n_in,
                              void* d_out, int out_size, void* d_ws, size_t ws_size,
                              hipStream_t stream) {
  (void)in_sizes; (void)n_in; (void)out_size; (void)ws_size;
  const float* x       = (const float*)d_in[0];
  const float* obs_w0  = (const float*)d_in[1];
  const float* obs_b0  = (const float*)d_in[2];
  const float* obs_w1  = (const float*)d_in[3];
  const float* obs_b1  = (const float*)d_in[4];
  const float* obs_w2  = (const float*)d_in[5];
  const float* obs_b2  = (const float*)d_in[6];
  const float* gru_wih = (const float*)d_in[7];
  const float* gru_whh = (const float*)d_in[8];
  const float* gru_bih = (const float*)d_in[9];
  const float* gru_bhh = (const float*)d_in[10];
  const float* m2q_w0  = (const float*)d_in[11];
  const float* m2q_b0  = (const float*)d_in[12];
  const float* m2q_w1  = (const float*)d_in[13];
  const float* m2q_b1  = (const float*)d_in[14];
  const float* m2q_w2  = (const float*)d_in[15];
  const float* m2q_b2  = (const float*)d_in[16];
  const float* q2m_w0  = (const float*)d_in[17];
  const float* q2m_b0  = (const float*)d_in[18];
  const float* q2m_w1  = (const float*)d_in[19];
  const float* q2m_b1  = (const float*)d_in[20];
  const float* q2m_w2  = (const float*)d_in[21];
  const float* q2m_b2  = (const float*)d_in[22];
  const float* act_w   = (const float*)d_in[23];
  const float* act_b   = (const float*)d_in[24];

  // workspace layout (bytes): xcodes@0 (2MB), qcodes@2MB (2MB),
  // GI@4MB (1.68MB), GHM@6MB (1.68MB), Y@8MB (0.42MB)  => ~8.5 MB total
  char* ws = (char*)d_ws;
  unsigned short* xcodes = (unsigned short*)(ws);
  unsigned short* qcodes = (unsigned short*)(ws + (2u << 20));
  float* gip  = (float*)(ws + (4u << 20));
  float* ghm  = (float*)(ws + (6u << 20));
  float* ytab = (float*)(ws + (8u << 20));

  k_gi<<<26, 256, 0, stream>>>(gru_wih, gru_bih, gip);
  k_mtab<<<26, 256, 0, stream>>>(q2m_w0, q2m_b0, q2m_w1, q2m_b1, q2m_w2, q2m_b2,
                                 gru_whh, gru_bhh, act_w, act_b, ghm, ytab);
  k_obs<<<NELEM / 256, 256, 0, stream>>>(x, obs_w0, obs_b0, obs_w1, obs_b1,
                                         obs_w2, obs_b2, xcodes);
  k_scan<<<(B_DIM * 16) / 64, 64, 0, stream>>>(xcodes, ghm, gip,
                                               m2q_w0, m2q_b0, m2q_w1, m2q_b1,
                                               m2q_w2, m2q_b2, qcodes);
  k_out<<<(NELEM * 4) / 256, 256, 0, stream>>>(qcodes, ytab, (float*)d_out);
}

// Round 2
// 1123.798 us; speedup vs baseline: 1.0034x; 1.0034x over previous
//
#include <hip/hip_runtime.h>

// QBN_GRU_Base on MI355X.
// Ternary bottlenecks (dim 8) make the recurrence finite-state:
//   xq, q in {-1,0,1}^8 -> 6561 codes. Memoize
//     GI[code][64]   = xq@wih.T + bih            (packed [i*4+{r,z,n,pad}])
//     GHM[code][64]  = {m@whh.T + bhh, m}        (packed [i*4+{r,z,n,m}], row 6561 = h0 state)
//     Y[code][16]    = tanh(m@act_w.T + act_b)
// Scan step = 2 table-row loads + gates + m2q (640 MAC) across 16 lanes/elem.
// R2 change: digit reduction = one bpermute round (8 independent gathers) +
// local exact tree-sum of 3^k*256-scaled digits -> direct byte offset.
// Numerics: XLA/Eigen rational tanh, logistic = 0.5+0.5*tanh(0.5x), fma dots —
// all float expressions identical to the absmax==0.0 round-1 kernel.

#define T_DIM 512
#define B_DIM 2048
#define NELEM (T_DIM * B_DIM)

__device__ __forceinline__ float tanh_xla(float x) {
  // Eigen/XLA generic_fast_tanh_float
  const float kClamp = 7.99881172180175781f;
  float xc = fminf(fmaxf(x, -kClamp), kClamp);
  float x2 = xc * xc;
  float p = fmaf(x2, -2.76076847742355e-16f, 2.00018790482477e-13f);
  p = fmaf(x2, p, -8.60467152213735e-11f);
  p = fmaf(x2, p, 5.12229709037114e-08f);
  p = fmaf(x2, p, 1.48572235717979e-05f);
  p = fmaf(x2, p, 6.37261928875436e-04f);
  p = fmaf(x2, p, 4.89352455891786e-03f);
  p = xc * p;
  float q = fmaf(x2, 1.19825839466702e-06f, 1.18534705686654e-04f);
  q = fmaf(x2, q, 2.26843463243900e-03f);
  q = fmaf(x2, q, 4.89352518554385e-03f);
  float r = p / q;
  return (fabsf(x) < 0.0004f) ? x : r;
}

__device__ __forceinline__ float sigmoid_xla(float x) {
  return 0.5f + 0.5f * tanh_xla(0.5f * x);
}

__device__ __forceinline__ int ternary_digit(float v) {
  float soft = 1.5f * tanh_xla(v) + 0.5f * tanh_xla(-3.0f * v);
  return (int)rintf(soft) + 1;
}

// ---------------- K1: obs encoder -> xcode[T*B] ----------------
__global__ __launch_bounds__(256) void k_obs(
    const float* __restrict__ x,
    const float* __restrict__ w0, const float* __restrict__ b0,
    const float* __restrict__ w1, const float* __restrict__ b1,
    const float* __restrict__ w2, const float* __restrict__ b2,
    unsigned short* __restrict__ xcodes) {
  int e = blockIdx.x * 256 + threadIdx.x;  // grid is exact
  const float* xr = x + (size_t)e * 64;
  float xv[64];
#pragma unroll
  for (int j = 0; j < 64; j += 4) {
    float4 v = *reinterpret_cast<const float4*>(xr + j);
    xv[j] = v.x; xv[j + 1] = v.y; xv[j + 2] = v.z; xv[j + 3] = v.w;
  }
  float h1[28];
#pragma unroll
  for (int k = 0; k < 28; ++k) {
    float acc = 0.0f;
#pragma unroll
    for (int j = 0; j < 64; ++j) acc = fmaf(w0[k * 64 + j], xv[j], acc);
    h1[k] = tanh_xla(acc + b0[k]);
  }
  float h2[28];
#pragma unroll
  for (int k = 0; k < 28; ++k) {
    float acc = 0.0f;
#pragma unroll
    for (int j = 0; j < 28; ++j) acc = fmaf(w1[k * 28 + j], h1[j], acc);
    h2[k] = tanh_xla(acc + b1[k]);
  }
  const int p3[8] = {1, 3, 9, 27, 81, 243, 729, 2187};
  unsigned code = 0;
#pragma unroll
  for (int k = 0; k < 8; ++k) {
    float acc = 0.0f;
#pragma unroll
    for (int j = 0; j < 28; ++j) acc = fmaf(w2[k * 28 + j], h2[j], acc);
    code += (unsigned)(ternary_digit(acc + b2[k]) * p3[k]);
  }
  xcodes[e] = (unsigned short)code;
}

// ---------------- K2: GI table [6561][64] ----------------
__global__ __launch_bounds__(256) void k_gi(
    const float* __restrict__ wih, const float* __restrict__ bih,
    float* __restrict__ gip) {
  int c = blockIdx.x * 256 + threadIdx.x;
  if (c >= 6561) return;
  float q[8];
  unsigned cc = (unsigned)c;
#pragma unroll
  for (int k = 0; k < 8; ++k) { q[k] = (float)((int)(cc % 3u) - 1); cc /= 3u; }
#pragma unroll
  for (int i = 0; i < 16; ++i) {
    float gr = 0.f, gz = 0.f, gn = 0.f;
#pragma unroll
    for (int j = 0; j < 8; ++j) {
      gr = fmaf(wih[i * 8 + j], q[j], gr);
      gz = fmaf(wih[(16 + i) * 8 + j], q[j], gz);
      gn = fmaf(wih[(32 + i) * 8 + j], q[j], gn);
    }
    float4 o;
    o.x = gr + bih[i]; o.y = gz + bih[16 + i]; o.z = gn + bih[32 + i]; o.w = 0.f;
    *reinterpret_cast<float4*>(gip + (size_t)c * 64 + i * 4) = o;
  }
}

// ---------------- K3: GHM [6562][64] + Y [6561][16] ----------------
__global__ __launch_bounds__(256) void k_mtab(
    const float* __restrict__ q2m_w0, const float* __restrict__ q2m_b0,
    const float* __restrict__ q2m_w1, const float* __restrict__ q2m_b1,
    const float* __restrict__ q2m_w2, const float* __restrict__ q2m_b2,
    const float* __restrict__ whh, const float* __restrict__ bhh,
    const float* __restrict__ act_w, const float* __restrict__ act_b,
    float* __restrict__ ghm, float* __restrict__ ytab) {
  int c = blockIdx.x * 256 + threadIdx.x;
  if (c > 6561) return;
  float m[16];
  if (c == 6561) {
#pragma unroll
    for (int i = 0; i < 16; ++i) m[i] = 0.0f;  // h0 = 0
  } else {
    float q[8];
    unsigned cc = (unsigned)c;
#pragma unroll
    for (int k = 0; k < 8; ++k) { q[k] = (float)((int)(cc % 3u) - 1); cc /= 3u; }
    float a[16];
#pragma unroll
    for (int i = 0; i < 16; ++i) {
      float acc = 0.f;
#pragma unroll
      for (int j = 0; j < 8; ++j) acc = fmaf(q2m_w0[i * 8 + j], q[j], acc);
      a[i] = tanh_xla(acc + q2m_b0[i]);
    }
    float d[16];
#pragma unroll
    for (int i = 0; i < 16; ++i) {
      float acc = 0.f;
#pragma unroll
      for (int j = 0; j < 16; ++j) acc = fmaf(q2m_w1[i * 16 + j], a[j], acc);
      d[i] = tanh_xla(acc + q2m_b1[i]);
    }
#pragma unroll
    for (int i = 0; i < 16; ++i) {
      float acc = 0.f;
#pragma unroll
      for (int j = 0; j < 16; ++j) acc = fmaf(q2m_w2[i * 16 + j], d[j], acc);
      m[i] = tanh_xla(acc + q2m_b2[i]);
    }
  }
#pragma unroll
  for (int i = 0; i < 16; ++i) {
    float gr = 0.f, gz = 0.f, gn = 0.f;
#pragma unroll
    for (int j = 0; j < 16; ++j) {
      gr = fmaf(whh[i * 16 + j], m[j], gr);
      gz = fmaf(whh[(16 + i) * 16 + j], m[j], gz);
      gn = fmaf(whh[(32 + i) * 16 + j], m[j], gn);
    }
    float4 o;
    o.x = gr + bhh[i]; o.y = gz + bhh[16 + i]; o.z = gn + bhh[32 + i]; o.w = m[i];
    *reinterpret_cast<float4*>(ghm + (size_t)c * 64 + i * 4) = o;
  }
  if (c < 6561) {
#pragma unroll
    for (int i = 0; i < 16; ++i) {
      float acc = 0.f;
#pragma unroll
      for (int j = 0; j < 16; ++j) acc = fmaf(act_w[i * 16 + j], m[j], acc);
      ytab[(size_t)c * 16 + i] = tanh_xla(acc + act_b[i]);
    }
  }
}

// ---------------- K4: the scan. 16 lanes per batch element ----------------
__device__ __forceinline__ float bcast16(int base4, int j, float v) {
  // broadcast lane ((lane&~15)+j)'s v to all lanes of the 16-group
  return __int_as_float(
      __builtin_amdgcn_ds_bpermute(base4 + 4 * j, __float_as_int(v)));
}

__global__ __launch_bounds__(64) void k_scan(
    const unsigned short* __restrict__ xcodes,
    const float* __restrict__ ghm,  // [6562][64]
    const float* __restrict__ gip,  // [6561][64]
    const float* __restrict__ m2q_w0, const float* __restrict__ m2q_b0,
    const float* __restrict__ m2q_w1, const float* __restrict__ m2q_b1,
    const float* __restrict__ m2q_w2, const float* __restrict__ m2q_b2,
    unsigned short* __restrict__ qcodes) {
  int lane = threadIdx.x & 15;
  int b = (blockIdx.x * 64 + threadIdx.x) >> 4;  // 0..2047
  int base4 = (threadIdx.x & 48) << 2;           // bpermute byte addr of group lane 0
  int lane16 = lane * 16;                        // byte offset of this lane's float4

  // per-lane m2q weight rows
  float w0r[16], w1r[16], w2r[16];
#pragma unroll
  for (int j = 0; j < 16; j += 4) {
    float4 a = *reinterpret_cast<const float4*>(m2q_w0 + lane * 16 + j);
    w0r[j] = a.x; w0r[j + 1] = a.y; w0r[j + 2] = a.z; w0r[j + 3] = a.w;
    float4 bq = *reinterpret_cast<const float4*>(m2q_w1 + lane * 16 + j);
    w1r[j] = bq.x; w1r[j + 1] = bq.y; w1r[j + 2] = bq.z; w1r[j + 3] = bq.w;
    float4 cq = *reinterpret_cast<const float4*>(m2q_w2 + (lane & 7) * 16 + j);
    w2r[j] = cq.x; w2r[j + 1] = cq.y; w2r[j + 2] = cq.z; w2r[j + 3] = cq.w;
  }
  float b0l = m2q_b0[lane], b1l = m2q_b1[lane], b2l = m2q_b2[lane & 7];
  // digit weight: 3^(lane&7) * 256 as float (exact)
  int p3i = 1;
  for (int k = 0; k < (lane & 7); ++k) p3i *= 3;
  float w3f = (float)(p3i * 256);
  const int kOffBias = 3280 * 256;  // sum of 3^k*256, k=0..7

  const char* ghmB = (const char*)ghm;
  const char* gipB = (const char*)gip;

  int qoff = 6561 * 256;  // byte offset of initial-state row
  unsigned xc = xcodes[b];
  float4 i4 = *reinterpret_cast<const float4*>(gipB + (unsigned)(((int)xc << 8) + lane16));

  for (int t = 0; t < T_DIM; ++t) {
    float4 g4 = *reinterpret_cast<const float4*>(ghmB + (unsigned)(qoff + lane16));
    // prefetch next step's GI row (independent of qprev chain)
    int tn = (t + 1 < T_DIM) ? t + 1 : T_DIM - 1;
    unsigned xcn = xcodes[tn * B_DIM + b];
    float4 i4n = *reinterpret_cast<const float4*>(gipB + (unsigned)(((int)xcn << 8) + lane16));

    float r = sigmoid_xla(i4.x + g4.x);
    float z = sigmoid_xla(i4.y + g4.y);
    float n = tanh_xla(fmaf(r, g4.z, i4.z));
    float h = (1.0f - z) * n + z * g4.w;

    float acc = 0.f;
#pragma unroll
    for (int j = 0; j < 16; ++j) acc = fmaf(w0r[j], bcast16(base4, j, h), acc);
    float t0 = tanh_xla(acc + b0l);
    acc = 0.f;
#pragma unroll
    for (int j = 0; j < 16; ++j) acc = fmaf(w1r[j], bcast16(base4, j, t0), acc);
    float t1 = tanh_xla(acc + b1l);
    acc = 0.f;
#pragma unroll
    for (int j = 0; j < 16; ++j) acc = fmaf(w2r[j], bcast16(base4, j, t1), acc);
    // ternary digit as float, pre-scaled by 3^k*256 (exact integers in fp32)
    float s = acc + b2l;
    float soft = 1.5f * tanh_xla(s) + 0.5f * tanh_xla(-3.0f * s);
    float valf = rintf(soft) * w3f;  // in {-1,0,1} * 3^k*256
    // one-hop gather of the 8 digit contributions + exact local tree sum
    float f0 = bcast16(base4, 0, valf), f1 = bcast16(base4, 1, valf);
    float f2 = bcast16(base4, 2, valf), f3 = bcast16(base4, 3, valf);
    float f4 = bcast16(base4, 4, valf), f5 = bcast16(base4, 5, valf);
    float f6 = bcast16(base4, 6, valf), f7 = bcast16(base4, 7, valf);
    float s0 = f0 + f1, s1 = f2 + f3, s2 = f4 + f5, s3 = f6 + f7;
    float st = (s0 + s1) + (s2 + s3);
    qoff = (int)st + kOffBias;  // byte offset = qcode*256

    if (lane == 0) qcodes[t * B_DIM + b] = (unsigned short)((unsigned)qoff >> 8);
    i4 = i4n;
  }
}

// ---------------- K5: output gather out[e] = Y[qcode[e]] ----------------
__global__ __launch_bounds__(256) void k_out(
    const unsigned short* __restrict__ qcodes,
    const float* __restrict__ ytab,
    float* __restrict__ out) {
  int i = blockIdx.x * 256 + threadIdx.x;  // over NELEM*4 float4s, grid exact
  int e = i >> 2, sub = i & 3;
  unsigned c = qcodes[e];
  float4 y = *reinterpret_cast<const float4*>(ytab + (size_t)c * 16 + sub * 4);
  reinterpret_cast<float4*>(out)[i] = y;
}

extern "C" void kernel_launch(void* const* d_in, const int* in_sizes, int n_in,
                              void* d_out, int out_size, void* d_ws, size_t ws_size,
                              hipStream_t stream) {
  (void)in_sizes; (void)n_in; (void)out_size; (void)ws_size;
  const float* x       = (const float*)d_in[0];
  const float* obs_w0  = (const float*)d_in[1];
  const float* obs_b0  = (const float*)d_in[2];
  const float* obs_w1  = (const float*)d_in[3];
  const float* obs_b1  = (const float*)d_in[4];
  const float* obs_w2  = (const float*)d_in[5];
  const float* obs_b2  = (const float*)d_in[6];
  const float* gru_wih = (const float*)d_in[7];
  const float* gru_whh = (const float*)d_in[8];
  const float* gru_bih = (const float*)d_in[9];
  const float* gru_bhh = (const float*)d_in[10];
  const float* m2q_w0  = (const float*)d_in[11];
  const float* m2q_b0  = (const float*)d_in[12];
  const float* m2q_w1  = (const float*)d_in[13];
  const float* m2q_b1  = (const float*)d_in[14];
  const float* m2q_w2  = (const float*)d_in[15];
  const float* m2q_b2  = (const float*)d_in[16];
  const float* q2m_w0  = (const float*)d_in[17];
  const float* q2m_b0  = (const float*)d_in[18];
  const float* q2m_w1  = (const float*)d_in[19];
  const float* q2m_b1  = (const float*)d_in[20];
  const float* q2m_w2  = (const float*)d_in[21];
  const float* q2m_b2  = (const float*)d_in[22];
  const float* act_w   = (const float*)d_in[23];
  const float* act_b   = (const float*)d_in[24];

  char* ws = (char*)d_ws;
  unsigned short* xcodes = (unsigned short*)(ws);
  unsigned short* qcodes = (unsigned short*)(ws + (2u << 20));
  float* gip  = (float*)(ws + (4u << 20));
  float* ghm  = (float*)(ws + (6u << 20));
  float* ytab = (float*)(ws + (8u << 20));

  k_gi<<<26, 256, 0, stream>>>(gru_wih, gru_bih, gip);
  k_mtab<<<26, 256, 0, stream>>>(q2m_w0, q2m_b0, q2m_w1, q2m_b1, q2m_w2, q2m_b2,
                                 gru_whh, gru_bhh, act_w, act_b, ghm, ytab);
  k_obs<<<NELEM / 256, 256, 0, stream>>>(x, obs_w0, obs_b0, obs_w1, obs_b1,
                                         obs_w2, obs_b2, xcodes);
  k_scan<<<(B_DIM * 16) / 64, 64, 0, stream>>>(xcodes, ghm, gip,
                                               m2q_w0, m2q_b0, m2q_w1, m2q_b1,
                                               m2q_w2, m2q_b2, qcodes);
  k_out<<<(NELEM * 4) / 256, 256, 0, stream>>>(qcodes, ytab, (float*)d_out);
}